// Round 14
// baseline (129.447 us; speedup 1.0000x reference)
//
#include <hip/hip_runtime.h>

#define NRES 64
#define GRID_CELLS (NRES * NRES * NRES)
#define TILE_CELLS 16384          // 4 z-planes x 64 x 64 ints per side
#define TPB 1024
#define QI 2                      // quad-iterations per thread in fill
#define FILL_QUADS (TPB * QI)     // 2048 quads = 8192 entries per block
#define ZBINS 64
#define NSLABS2 32                // slabs own 2 bz values each
#define GC 8                      // chunks per slab -> 256 scatter blocks
#define CAP 150016u               // slots per z-bin
#define MAXC 32
#define FXS 4194304.0f            // 2^22 fixed-point scale
#define INV_FXS (1.0f / 4194304.0f)
#define QS 2097152.0f             // 64 * 32768 position quantizer
typedef unsigned long long u64;
typedef unsigned u32;
typedef unsigned short u16;

// ws layout (main path):
//   cursors u32[64]        @ 0           (within-bin counts, memset 0)
//   bins    u64[64*150016] @ 4096        (76,808,192 B)
//   partial int[256*16384] @ 76,812,288  (16 MB)      total 93,589,504 B

__device__ __forceinline__ u32 quantc(float v) {
    return (u32)(v * QS + 0.5f);
}
__device__ __forceinline__ int cell_from_q(u32 q) {
    float s = (float)q * (1.0f / 32768.0f);
    int c = (int)(s - 0.5f);          // coords >= 3.2 so trunc == floor
    return min(max(c, 0), 63);
}

// One global read; entries held in registers; LDS counting-sort staging;
// coalesced contiguous run-copy to global bins.  (verified R13)
__global__ __launch_bounds__(TPB)
void fused_fill_kernel(const float* __restrict__ x, const float* __restrict__ xr,
                       int n, u32* __restrict__ cursor, u64* __restrict__ bins) {
    __shared__ u64 stage[FILL_QUADS * 4];          // 64 KB
    __shared__ u32 h[ZBINS];
    __shared__ u32 lb[ZBINS];
    __shared__ u32 gb[ZBINS];
    const int tid = threadIdx.x;
    if (tid < ZBINS) h[tid] = 0;
    __syncthreads();

    const int Q = n >> 2;
    const int GQ = 2 * Q;
    const int g0 = blockIdx.x * FILL_QUADS + tid;

    u64 ent[QI][4];
    u32 lsl[QI][4];
    bool val[QI];

#pragma unroll
    for (int it = 0; it < QI; ++it) {
        int g = g0 + it * TPB;
        val[it] = (g < GQ);
        if (val[it]) {
            int inx = (g < Q);
            const float* __restrict__ p = inx ? (x + 12 * (size_t)g)
                                              : (xr + 12 * (size_t)(g - Q));
            float4 a = ((const float4*)p)[0];
            float4 b = ((const float4*)p)[1];
            float4 c = ((const float4*)p)[2];
            u64 sgn = inx ? 0ull : (1ull << 63);
            float px[4] = {a.x, a.w, b.z, c.y};
            float py[4] = {a.y, b.x, b.w, c.z};
            float pz[4] = {a.z, b.y, c.x, c.w};
#pragma unroll
            for (int q = 0; q < 4; ++q) {
                u32 xq = quantc(px[q]);
                u32 yq = quantc(py[q]);
                u32 zq = quantc(pz[q]);
                ent[it][q] = (u64)xq | ((u64)yq << 21) | ((u64)zq << 42) | sgn;
                int bz = cell_from_q(zq);
                lsl[it][q] = atomicAdd(&h[bz], 1u);
            }
        }
    }
    __syncthreads();

    if (tid < 64) {
        u32 c = h[tid];
        u32 acc = c;
#pragma unroll
        for (int off = 1; off < 64; off <<= 1) {
            u32 o = __shfl_up(acc, off, 64);
            if (tid >= off) acc += o;
        }
        lb[tid] = acc - c;
        gb[tid] = c ? atomicAdd(&cursor[tid], c) : 0u;
    }
    __syncthreads();

#pragma unroll
    for (int it = 0; it < QI; ++it) {
        if (val[it]) {
#pragma unroll
            for (int q = 0; q < 4; ++q) {
                u64 v = ent[it][q];
                int bz = cell_from_q((u32)((v >> 42) & 0x1FFFFFu));
                stage[lb[bz] + lsl[it][q]] = v;
            }
        }
    }
    __syncthreads();

    const int wid = tid >> 6, lane = tid & 63;
    for (int b = wid; b < ZBINS; b += TPB / 64) {
        u32 cnt = h[b];
        u32 l0 = lb[b];
        u32 g  = gb[b];
        u64* __restrict__ dst = bins + (size_t)b * CAP;
        for (u32 i = lane; i < cnt; i += 64) {
            u32 slot = g + i;
            if (slot < CAP) dst[slot] = stage[l0 + i];
        }
    }
}

// Single-visit scatter with PACKED u64 LDS atomics.
// Two magnitude tiles (positive / negative side selected by entry sign bit)
// in one 128 KB LDS block; each stencil x-row (3 ints) covered by 2 aligned
// u64 adds with non-negative halves (no carry hazard; zero-half adds are
// harmless). Flush writes P - N so downstream stages are unchanged.
__global__ __launch_bounds__(TPB)
void bin_scatter_kernel(const u64* __restrict__ bins,
                        const u32* __restrict__ cursor,
                        int* __restrict__ partial) {
    __shared__ u64 tileLL[TILE_CELLS];   // 128 KB: [0..8191]=pos, [8192..]=neg
    int* intTile = (int*)tileLL;
    const int slab  = blockIdx.x / GC;
    const int chunk = blockIdx.x - slab * GC;

    for (int i = threadIdx.x; i < TILE_CELLS * 2 / 4; i += TPB)
        reinterpret_cast<int4*>(intTile)[i] = make_int4(0, 0, 0, 0);
    __syncthreads();

    const u32 b0 = (u32)(2 * slab), b1 = b0 + 1;
    u32 c0 = cursor[b0]; if (c0 > CAP) c0 = CAP;
    u32 c1 = cursor[b1]; if (c1 > CAP) c1 = CAP;
    u32 cnt = c0 + c1;
    u32 per = (cnt + (u32)GC - 1u) / (u32)GC;
    u32 i0 = (u32)chunk * per;
    u32 i1 = i0 + per;
    if (i1 > cnt) i1 = cnt;

    for (u32 i = i0 + threadIdx.x; i < i1; i += TPB) {
        u32 idx = (i < c0) ? (b0 * CAP + i) : (b1 * CAP + (i - c0));
        u64 v = bins[idx];
        float xs = (float)(u32)(v & 0x1FFFFFu) * (1.0f / 32768.0f);
        float ys = (float)(u32)((v >> 21) & 0x1FFFFFu) * (1.0f / 32768.0f);
        float zs = (float)(u32)((v >> 42) & 0x1FFFFFu) * (1.0f / 32768.0f);
        u64* __restrict__ t64 = tileLL + ((v >> 63) ? 8192 : 0);

        int bx = (int)(xs - 0.5f);
        int by = (int)(ys - 0.5f);
        int bz = (int)(zs - 0.5f);
        float fx = xs - (float)bx, fy = ys - (float)by, fz = zs - (float)bz;

        float wx0 = 0.5f * (1.5f - fx) * (1.5f - fx);
        float wx1 = 0.75f - (fx - 1.0f) * (fx - 1.0f);
        float wx2 = 0.5f * (fx - 0.5f) * (fx - 0.5f);
        float wy0 = 0.5f * (1.5f - fy) * (1.5f - fy);
        float wy1 = 0.75f - (fy - 1.0f) * (fy - 1.0f);
        float wy2 = 0.5f * (fy - 0.5f) * (fy - 0.5f);
        float wzv[3];
        wzv[0] = 0.5f * (1.5f - fz) * (1.5f - fz);
        wzv[1] = 0.75f - (fz - 1.0f) * (fz - 1.0f);
        wzv[2] = 0.5f * (fz - 0.5f) * (fz - 0.5f);

        // NOTE: rows are (y-major within row): ints (a, a+1, a+2) = wy0,wy1,wy2
        float wxr[3] = {wx0, wx1, wx2};
        float wyr[3] = {wy0, wy1, wy2};

        int basexy = bx * 64 + by;
        int zlo = bz - 2 * slab;            // 0 or 1, always valid
#pragma unroll
        for (int k = 0; k < 3; ++k) {
            float wzS = wzv[k] * FXS;
            int a0 = (zlo + k) * 4096 + basexy;
#pragma unroll
            for (int i2 = 0; i2 < 3; ++i2) {
                float wxz = wxr[i2] * wzS;
                u32 q0 = (u32)__float2int_rn(wyr[0] * wxz);
                u32 q1 = (u32)__float2int_rn(wyr[1] * wxz);
                u32 q2 = (u32)__float2int_rn(wyr[2] * wxz);
                int a = a0 + i2 * 64;       // ints a, a+1, a+2 get q0,q1,q2
                int e = a & 1;
                int w0 = a >> 1;            // u64 word covering (a&~1, a&~1+1)
                u64 p0 = e ? ((u64)q0 << 32) : ((u64)q0 | ((u64)q1 << 32));
                u64 p1 = e ? ((u64)q1 | ((u64)q2 << 32)) : (u64)q2;
                atomicAdd(&t64[w0], p0);
                atomicAdd(&t64[w0 + 1], p1);
            }
        }
    }
    __syncthreads();

    // flush P - N
    int* __restrict__ dst = partial + (size_t)blockIdx.x * TILE_CELLS;
    for (int i = threadIdx.x; i < TILE_CELLS / 4; i += TPB) {
        int4 P = reinterpret_cast<const int4*>(intTile)[i];
        int4 N = reinterpret_cast<const int4*>(intTile + TILE_CELLS)[i];
        int4 d;
        d.x = P.x - N.x; d.y = P.y - N.y; d.z = P.z - N.z; d.w = P.w - N.w;
        reinterpret_cast<int4*>(dst)[i] = d;
    }
}

// Each cell z gets contributions from slab s0=z>>1 (plane z&1) and slab
// s0-1 (plane (z&1)+2), each replicated over GC chunks.
__global__ void int_reduce_kernel(const int* __restrict__ partial,
                                  float* __restrict__ out) {
    int tid = blockIdx.x * blockDim.x + threadIdx.x;   // 0 .. 262143
    int z  = tid >> 12;          // 0..63
    int xy = tid & 4095;
    int s0 = z >> 1, zl0 = z & 1;
    int sum = 0;
    const int* __restrict__ p0 =
        partial + (size_t)(s0 * GC) * TILE_CELLS + zl0 * 4096 + xy;
#pragma unroll
    for (int g = 0; g < GC; ++g) sum += p0[(size_t)g * TILE_CELLS];
    if (s0 > 0) {
        const int* __restrict__ p1 =
            partial + (size_t)((s0 - 1) * GC) * TILE_CELLS + (zl0 + 2) * 4096 + xy;
#pragma unroll
        for (int g = 0; g < GC; ++g) sum += p1[(size_t)g * TILE_CELLS];
    }
    float v = fabsf((float)sum) * INV_FXS;
#pragma unroll
    for (int off = 32; off > 0; off >>= 1) v += __shfl_down(v, off, 64);
    __shared__ float wsum[4];
    int lane = threadIdx.x & 63, wid = threadIdx.x >> 6;
    if (lane == 0) wsum[wid] = v;
    __syncthreads();
    if (threadIdx.x == 0) atomicAdd(out, wsum[0] + wsum[1] + wsum[2] + wsum[3]);
}

// ---------------- fallback path (round-2 kernels, verified correct) --------

__global__ __launch_bounds__(TPB)
void slab_scatter_kernel(const float* __restrict__ x,
                         const float* __restrict__ xr,
                         int n, int C, float* __restrict__ partial) {
    __shared__ float tile[TILE_CELLS];
    const int slab  = blockIdx.x / C;
    const int chunk = blockIdx.x - slab * C;
    const int z0 = slab * 4;

    for (int i = threadIdx.x; i < TILE_CELLS; i += TPB) tile[i] = 0.0f;
    __syncthreads();

    const int per = (n + C - 1) / C;
    const int p0 = chunk * per;
    const int p1 = min(n, p0 + per);

    for (int f = 0; f < 2; ++f) {
        const float* __restrict__ p = f ? xr : x;
        const float sgn = f ? -1.0f : 1.0f;
        for (int i = p0 + (int)threadIdx.x; i < p1; i += TPB) {
            float zs = p[3 * i + 2] * 64.0f;
            int bz = (int)floorf(zs - 0.5f);
            int zlo = bz - z0;
            if (zlo > 3 || zlo + 2 < 0) continue;

            float xs = p[3 * i + 0] * 64.0f;
            float ys = p[3 * i + 1] * 64.0f;
            int bx = (int)floorf(xs - 0.5f);
            int by = (int)floorf(ys - 0.5f);
            float fx = xs - (float)bx, fy = ys - (float)by, fz = zs - (float)bz;

            float wx0 = 0.5f * (1.5f - fx) * (1.5f - fx);
            float wx1 = 0.75f - (fx - 1.0f) * (fx - 1.0f);
            float wx2 = 0.5f * (fx - 0.5f) * (fx - 0.5f);
            float wy0 = 0.5f * (1.5f - fy) * (1.5f - fy);
            float wy1 = 0.75f - (fy - 1.0f) * (fy - 1.0f);
            float wy2 = 0.5f * (fy - 0.5f) * (fy - 0.5f);
            float wzv[3];
            wzv[0] = 0.5f * (1.5f - fz) * (1.5f - fz);
            wzv[1] = 0.75f - (fz - 1.0f) * (fz - 1.0f);
            wzv[2] = 0.5f * (fz - 0.5f) * (fz - 0.5f);

            float wxy[9];
            wxy[0] = sgn * wx0 * wy0; wxy[1] = sgn * wx0 * wy1; wxy[2] = sgn * wx0 * wy2;
            wxy[3] = sgn * wx1 * wy0; wxy[4] = sgn * wx1 * wy1; wxy[5] = sgn * wx1 * wy2;
            wxy[6] = sgn * wx2 * wy0; wxy[7] = sgn * wx2 * wy1; wxy[8] = sgn * wx2 * wy2;

            int base = (bx * 64 + by) * 4;
#pragma unroll
            for (int k = 0; k < 3; ++k) {
                int zl = zlo + k;
                if (zl < 0 || zl >= 4) continue;
                float wzk = wzv[k];
                int a = base + zl;
#pragma unroll
                for (int i2 = 0; i2 < 3; ++i2)
#pragma unroll
                    for (int j2 = 0; j2 < 3; ++j2)
                        atomicAdd(&tile[a + i2 * 256 + j2 * 4], wxy[i2 * 3 + j2] * wzk);
            }
        }
    }
    __syncthreads();

    float* __restrict__ dst = partial + (size_t)chunk * GRID_CELLS;
    for (int t = threadIdx.x; t < NRES * NRES; t += TPB) {
        float4 v = *reinterpret_cast<const float4*>(&tile[t * 4]);
        *reinterpret_cast<float4*>(&dst[t * 64 + z0]) = v;
    }
}

__global__ void reduce_kernel(const float* __restrict__ partial, int C,
                              float* __restrict__ out) {
    int cell = blockIdx.x * blockDim.x + threadIdx.x;
    float s = 0.0f;
    for (int c = 0; c < C; ++c) s += partial[(size_t)c * GRID_CELLS + cell];
    s = fabsf(s);
#pragma unroll
    for (int off = 32; off > 0; off >>= 1) s += __shfl_down(s, off, 64);
    __shared__ float wsum[4];
    int lane = threadIdx.x & 63, wid = threadIdx.x >> 6;
    if (lane == 0) wsum[wid] = s;
    __syncthreads();
    if (threadIdx.x == 0) atomicAdd(out, wsum[0] + wsum[1] + wsum[2] + wsum[3]);
}

extern "C" void kernel_launch(void* const* d_in, const int* in_sizes, int n_in,
                              void* d_out, int out_size, void* d_ws, size_t ws_size,
                              hipStream_t stream) {
    const float* x  = (const float*)d_in[0];
    const float* xr = (const float*)d_in[1];
    float* out = (float*)d_out;
    char* ws = (char*)d_ws;

    int n = in_sizes[0] / 3;  // 4,000,000

    const size_t OFF_CUR  = 0;
    const size_t OFF_BINS = 4096;
    const size_t binsBytes = (size_t)ZBINS * CAP * sizeof(u64);    // 76,808,192
    const size_t OFF_PART = OFF_BINS + binsBytes;                  // 76,812,288
    const size_t partBytes = (size_t)NSLABS2 * GC * TILE_CELLS * 4; // 16 MB
    const size_t gridBytes = (size_t)GRID_CELLS * sizeof(float);

    hipMemsetAsync(out, 0, sizeof(float), stream);

    if ((n & 3) == 0 && (u32)(2 * n) <= ZBINS * (CAP - 10000u)
        && ws_size >= OFF_PART + partBytes) {
        u32* cursor  = (u32*)(ws + OFF_CUR);
        u64* bins    = (u64*)(ws + OFF_BINS);
        int* partial = (int*)(ws + OFF_PART);

        int GQ = (n >> 2) * 2;
        int fillBlocks = (GQ + FILL_QUADS - 1) / FILL_QUADS;       // 977

        hipMemsetAsync(cursor, 0, ZBINS * sizeof(u32), stream);
        fused_fill_kernel<<<fillBlocks, TPB, 0, stream>>>(x, xr, n, cursor, bins);
        bin_scatter_kernel<<<NSLABS2 * GC, TPB, 0, stream>>>(bins, cursor, partial);
        int_reduce_kernel<<<GRID_CELLS / 256, 256, 0, stream>>>(partial, out);
    } else {
        float* partial = (float*)ws;
        int C = (int)(ws_size / gridBytes);
        if (C > MAXC) C = MAXC;
        if (C < 1) C = 1;
        slab_scatter_kernel<<<16 * C, TPB, 0, stream>>>(x, xr, n, C, partial);
        reduce_kernel<<<GRID_CELLS / 256, 256, 0, stream>>>(partial, C, out);
    }
}

// Round 15
// 120.636 us; speedup vs baseline: 1.0730x; 1.0730x over previous
//
#include <hip/hip_runtime.h>

#define NRES 64
#define GRID_CELLS (NRES * NRES * NRES)
#define TILE_CELLS 16384          // 4 z-planes x 64 x 64 (64 KB of int)
#define TPB 1024
#define QI 2                      // quad-iterations per thread in fill
#define FILL_QUADS (TPB * QI)     // 2048 quads = 8192 entries per block
#define ZBINS 64
#define NSLABS2 32                // slabs own 2 bz values each
#define GC 8                      // chunks per slab -> 256 scatter blocks
#define CAP 150016u               // slots per z-bin
#define MAXC 32
#define FXS 4194304.0f            // 2^22 fixed-point scale
#define INV_FXS (1.0f / 4194304.0f)
#define QS 2097152.0f             // 64 * 32768 position quantizer
typedef unsigned long long u64;
typedef unsigned u32;
typedef unsigned short u16;

// ws layout (main path):
//   cursors u32[64]        @ 0           (within-bin counts, memset 0)
//   bins    u64[64*150016] @ 4096        (76,808,192 B)
//   partial int[256*16384] @ 76,812,288  (16 MB)      total 93,589,504 B

__device__ __forceinline__ u32 quantc(float v) {
    return (u32)(v * QS + 0.5f);
}
__device__ __forceinline__ int cell_from_q(u32 q) {
    float s = (float)q * (1.0f / 32768.0f);
    int c = (int)(s - 0.5f);          // coords >= 3.2 so trunc == floor
    return min(max(c, 0), 63);
}

// One global read; entries held in registers; LDS counting-sort staging;
// coalesced contiguous run-copy to global bins.  (verified R13)
__global__ __launch_bounds__(TPB)
void fused_fill_kernel(const float* __restrict__ x, const float* __restrict__ xr,
                       int n, u32* __restrict__ cursor, u64* __restrict__ bins) {
    __shared__ u64 stage[FILL_QUADS * 4];          // 64 KB
    __shared__ u32 h[ZBINS];
    __shared__ u32 lb[ZBINS];
    __shared__ u32 gb[ZBINS];
    const int tid = threadIdx.x;
    if (tid < ZBINS) h[tid] = 0;
    __syncthreads();

    const int Q = n >> 2;
    const int GQ = 2 * Q;
    const int g0 = blockIdx.x * FILL_QUADS + tid;

    u64 ent[QI][4];
    u32 lsl[QI][4];
    bool val[QI];

#pragma unroll
    for (int it = 0; it < QI; ++it) {
        int g = g0 + it * TPB;
        val[it] = (g < GQ);
        if (val[it]) {
            int inx = (g < Q);
            const float* __restrict__ p = inx ? (x + 12 * (size_t)g)
                                              : (xr + 12 * (size_t)(g - Q));
            float4 a = ((const float4*)p)[0];
            float4 b = ((const float4*)p)[1];
            float4 c = ((const float4*)p)[2];
            u64 sgn = inx ? 0ull : (1ull << 63);
            float px[4] = {a.x, a.w, b.z, c.y};
            float py[4] = {a.y, b.x, b.w, c.z};
            float pz[4] = {a.z, b.y, c.x, c.w};
#pragma unroll
            for (int q = 0; q < 4; ++q) {
                u32 xq = quantc(px[q]);
                u32 yq = quantc(py[q]);
                u32 zq = quantc(pz[q]);
                ent[it][q] = (u64)xq | ((u64)yq << 21) | ((u64)zq << 42) | sgn;
                int bz = cell_from_q(zq);
                lsl[it][q] = atomicAdd(&h[bz], 1u);
            }
        }
    }
    __syncthreads();

    if (tid < 64) {
        u32 c = h[tid];
        u32 acc = c;
#pragma unroll
        for (int off = 1; off < 64; off <<= 1) {
            u32 o = __shfl_up(acc, off, 64);
            if (tid >= off) acc += o;
        }
        lb[tid] = acc - c;
        gb[tid] = c ? atomicAdd(&cursor[tid], c) : 0u;
    }
    __syncthreads();

#pragma unroll
    for (int it = 0; it < QI; ++it) {
        if (val[it]) {
#pragma unroll
            for (int q = 0; q < 4; ++q) {
                u64 v = ent[it][q];
                int bz = cell_from_q((u32)((v >> 42) & 0x1FFFFFu));
                stage[lb[bz] + lsl[it][q]] = v;
            }
        }
    }
    __syncthreads();

    const int wid = tid >> 6, lane = tid & 63;
    for (int b = wid; b < ZBINS; b += TPB / 64) {
        u32 cnt = h[b];
        u32 l0 = lb[b];
        u32 g  = gb[b];
        u64* __restrict__ dst = bins + (size_t)b * CAP;
        for (u32 i = lane; i < cnt; i += 64) {
            u32 slot = g + i;
            if (slot < CAP) dst[slot] = stage[l0 + i];
        }
    }
}

// Single-visit scatter: slab s owns bz in {2s, 2s+1}; tile = 4 z-planes
// (global planes 2s .. 2s+3). zlo in {0,1} -> unconditional 27-atomic body.
// tile layout: zl*4096 + bx*64 + by (z-plane-major). 27x b32 LDS atomics is
// the measured DS-pipe optimum (R7 class-sort null, R10 -33% proportional,
// R14 b64 packing regression: cost scales with bank-slot accesses).
__global__ __launch_bounds__(TPB)
void bin_scatter_kernel(const u64* __restrict__ bins,
                        const u32* __restrict__ cursor,
                        int* __restrict__ partial) {
    __shared__ int tile[TILE_CELLS];   // 64 KB
    const int slab  = blockIdx.x / GC;
    const int chunk = blockIdx.x - slab * GC;

    for (int i = threadIdx.x; i < TILE_CELLS / 4; i += TPB)
        reinterpret_cast<int4*>(tile)[i] = make_int4(0, 0, 0, 0);
    __syncthreads();

    const u32 b0 = (u32)(2 * slab), b1 = b0 + 1;
    u32 c0 = cursor[b0]; if (c0 > CAP) c0 = CAP;
    u32 c1 = cursor[b1]; if (c1 > CAP) c1 = CAP;
    u32 cnt = c0 + c1;
    u32 per = (cnt + (u32)GC - 1u) / (u32)GC;
    u32 i0 = (u32)chunk * per;
    u32 i1 = i0 + per;
    if (i1 > cnt) i1 = cnt;

    for (u32 i = i0 + threadIdx.x; i < i1; i += TPB) {
        u32 idx = (i < c0) ? (b0 * CAP + i) : (b1 * CAP + (i - c0));
        u64 v = bins[idx];
        float xs = (float)(u32)(v & 0x1FFFFFu) * (1.0f / 32768.0f);
        float ys = (float)(u32)((v >> 21) & 0x1FFFFFu) * (1.0f / 32768.0f);
        float zs = (float)(u32)((v >> 42) & 0x1FFFFFu) * (1.0f / 32768.0f);
        float fsgn = (v >> 63) ? -FXS : FXS;

        int bx = (int)(xs - 0.5f);
        int by = (int)(ys - 0.5f);
        int bz = (int)(zs - 0.5f);
        float fx = xs - (float)bx, fy = ys - (float)by, fz = zs - (float)bz;

        float wx0 = 0.5f * (1.5f - fx) * (1.5f - fx);
        float wx1 = 0.75f - (fx - 1.0f) * (fx - 1.0f);
        float wx2 = 0.5f * (fx - 0.5f) * (fx - 0.5f);
        float wy0 = 0.5f * (1.5f - fy) * (1.5f - fy);
        float wy1 = 0.75f - (fy - 1.0f) * (fy - 1.0f);
        float wy2 = 0.5f * (fy - 0.5f) * (fy - 0.5f);
        float wzv[3];
        wzv[0] = 0.5f * (1.5f - fz) * (1.5f - fz);
        wzv[1] = 0.75f - (fz - 1.0f) * (fz - 1.0f);
        wzv[2] = 0.5f * (fz - 0.5f) * (fz - 0.5f);

        float wxy[9];
        wxy[0] = wx0 * wy0; wxy[1] = wx0 * wy1; wxy[2] = wx0 * wy2;
        wxy[3] = wx1 * wy0; wxy[4] = wx1 * wy1; wxy[5] = wx1 * wy2;
        wxy[6] = wx2 * wy0; wxy[7] = wx2 * wy1; wxy[8] = wx2 * wy2;

        int basexy = bx * 64 + by;
        int zlo = bz - 2 * slab;            // 0 or 1, always valid
#pragma unroll
        for (int k = 0; k < 3; ++k) {
            float wzS = wzv[k] * fsgn;
            int a = (zlo + k) * 4096 + basexy;
#pragma unroll
            for (int i2 = 0; i2 < 3; ++i2)
#pragma unroll
                for (int j2 = 0; j2 < 3; ++j2)
                    atomicAdd(&tile[a + i2 * 64 + j2],
                              __float2int_rn(wxy[i2 * 3 + j2] * wzS));
        }
    }
    __syncthreads();

    int* __restrict__ dst = partial + (size_t)blockIdx.x * TILE_CELLS;
    for (int i = threadIdx.x; i < TILE_CELLS / 4; i += TPB)
        reinterpret_cast<int4*>(dst)[i] = reinterpret_cast<const int4*>(tile)[i];
}

// Each cell z gets contributions from slab s0=z>>1 (plane z&1) and slab
// s0-1 (plane (z&1)+2), each replicated over GC chunks.
__global__ void int_reduce_kernel(const int* __restrict__ partial,
                                  float* __restrict__ out) {
    int tid = blockIdx.x * blockDim.x + threadIdx.x;   // 0 .. 262143
    int z  = tid >> 12;          // 0..63
    int xy = tid & 4095;
    int s0 = z >> 1, zl0 = z & 1;
    int sum = 0;
    const int* __restrict__ p0 =
        partial + (size_t)(s0 * GC) * TILE_CELLS + zl0 * 4096 + xy;
#pragma unroll
    for (int g = 0; g < GC; ++g) sum += p0[(size_t)g * TILE_CELLS];
    if (s0 > 0) {
        const int* __restrict__ p1 =
            partial + (size_t)((s0 - 1) * GC) * TILE_CELLS + (zl0 + 2) * 4096 + xy;
#pragma unroll
        for (int g = 0; g < GC; ++g) sum += p1[(size_t)g * TILE_CELLS];
    }
    float v = fabsf((float)sum) * INV_FXS;
#pragma unroll
    for (int off = 32; off > 0; off >>= 1) v += __shfl_down(v, off, 64);
    __shared__ float wsum[4];
    int lane = threadIdx.x & 63, wid = threadIdx.x >> 6;
    if (lane == 0) wsum[wid] = v;
    __syncthreads();
    if (threadIdx.x == 0) atomicAdd(out, wsum[0] + wsum[1] + wsum[2] + wsum[3]);
}

// ---------------- fallback path (round-2 kernels, verified correct) --------

__global__ __launch_bounds__(TPB)
void slab_scatter_kernel(const float* __restrict__ x,
                         const float* __restrict__ xr,
                         int n, int C, float* __restrict__ partial) {
    __shared__ float tile[TILE_CELLS];
    const int slab  = blockIdx.x / C;
    const int chunk = blockIdx.x - slab * C;
    const int z0 = slab * 4;

    for (int i = threadIdx.x; i < TILE_CELLS; i += TPB) tile[i] = 0.0f;
    __syncthreads();

    const int per = (n + C - 1) / C;
    const int p0 = chunk * per;
    const int p1 = min(n, p0 + per);

    for (int f = 0; f < 2; ++f) {
        const float* __restrict__ p = f ? xr : x;
        const float sgn = f ? -1.0f : 1.0f;
        for (int i = p0 + (int)threadIdx.x; i < p1; i += TPB) {
            float zs = p[3 * i + 2] * 64.0f;
            int bz = (int)floorf(zs - 0.5f);
            int zlo = bz - z0;
            if (zlo > 3 || zlo + 2 < 0) continue;

            float xs = p[3 * i + 0] * 64.0f;
            float ys = p[3 * i + 1] * 64.0f;
            int bx = (int)floorf(xs - 0.5f);
            int by = (int)floorf(ys - 0.5f);
            float fx = xs - (float)bx, fy = ys - (float)by, fz = zs - (float)bz;

            float wx0 = 0.5f * (1.5f - fx) * (1.5f - fx);
            float wx1 = 0.75f - (fx - 1.0f) * (fx - 1.0f);
            float wx2 = 0.5f * (fx - 0.5f) * (fx - 0.5f);
            float wy0 = 0.5f * (1.5f - fy) * (1.5f - fy);
            float wy1 = 0.75f - (fy - 1.0f) * (fy - 1.0f);
            float wy2 = 0.5f * (fy - 0.5f) * (fy - 0.5f);
            float wzv[3];
            wzv[0] = 0.5f * (1.5f - fz) * (1.5f - fz);
            wzv[1] = 0.75f - (fz - 1.0f) * (fz - 1.0f);
            wzv[2] = 0.5f * (fz - 0.5f) * (fz - 0.5f);

            float wxy[9];
            wxy[0] = sgn * wx0 * wy0; wxy[1] = sgn * wx0 * wy1; wxy[2] = sgn * wx0 * wy2;
            wxy[3] = sgn * wx1 * wy0; wxy[4] = sgn * wx1 * wy1; wxy[5] = sgn * wx1 * wy2;
            wxy[6] = sgn * wx2 * wy0; wxy[7] = sgn * wx2 * wy1; wxy[8] = sgn * wx2 * wy2;

            int base = (bx * 64 + by) * 4;
#pragma unroll
            for (int k = 0; k < 3; ++k) {
                int zl = zlo + k;
                if (zl < 0 || zl >= 4) continue;
                float wzk = wzv[k];
                int a = base + zl;
#pragma unroll
                for (int i2 = 0; i2 < 3; ++i2)
#pragma unroll
                    for (int j2 = 0; j2 < 3; ++j2)
                        atomicAdd(&tile[a + i2 * 256 + j2 * 4], wxy[i2 * 3 + j2] * wzk);
            }
        }
    }
    __syncthreads();

    float* __restrict__ dst = partial + (size_t)chunk * GRID_CELLS;
    for (int t = threadIdx.x; t < NRES * NRES; t += TPB) {
        float4 v = *reinterpret_cast<const float4*>(&tile[t * 4]);
        *reinterpret_cast<float4*>(&dst[t * 64 + z0]) = v;
    }
}

__global__ void reduce_kernel(const float* __restrict__ partial, int C,
                              float* __restrict__ out) {
    int cell = blockIdx.x * blockDim.x + threadIdx.x;
    float s = 0.0f;
    for (int c = 0; c < C; ++c) s += partial[(size_t)c * GRID_CELLS + cell];
    s = fabsf(s);
#pragma unroll
    for (int off = 32; off > 0; off >>= 1) s += __shfl_down(s, off, 64);
    __shared__ float wsum[4];
    int lane = threadIdx.x & 63, wid = threadIdx.x >> 6;
    if (lane == 0) wsum[wid] = s;
    __syncthreads();
    if (threadIdx.x == 0) atomicAdd(out, wsum[0] + wsum[1] + wsum[2] + wsum[3]);
}

extern "C" void kernel_launch(void* const* d_in, const int* in_sizes, int n_in,
                              void* d_out, int out_size, void* d_ws, size_t ws_size,
                              hipStream_t stream) {
    const float* x  = (const float*)d_in[0];
    const float* xr = (const float*)d_in[1];
    float* out = (float*)d_out;
    char* ws = (char*)d_ws;

    int n = in_sizes[0] / 3;  // 4,000,000

    const size_t OFF_CUR  = 0;
    const size_t OFF_BINS = 4096;
    const size_t binsBytes = (size_t)ZBINS * CAP * sizeof(u64);    // 76,808,192
    const size_t OFF_PART = OFF_BINS + binsBytes;                  // 76,812,288
    const size_t partBytes = (size_t)NSLABS2 * GC * TILE_CELLS * 4; // 16 MB
    const size_t gridBytes = (size_t)GRID_CELLS * sizeof(float);

    hipMemsetAsync(out, 0, sizeof(float), stream);

    if ((n & 3) == 0 && (u32)(2 * n) <= ZBINS * (CAP - 10000u)
        && ws_size >= OFF_PART + partBytes) {
        u32* cursor  = (u32*)(ws + OFF_CUR);
        u64* bins    = (u64*)(ws + OFF_BINS);
        int* partial = (int*)(ws + OFF_PART);

        int GQ = (n >> 2) * 2;
        int fillBlocks = (GQ + FILL_QUADS - 1) / FILL_QUADS;       // 977

        hipMemsetAsync(cursor, 0, ZBINS * sizeof(u32), stream);
        fused_fill_kernel<<<fillBlocks, TPB, 0, stream>>>(x, xr, n, cursor, bins);
        bin_scatter_kernel<<<NSLABS2 * GC, TPB, 0, stream>>>(bins, cursor, partial);
        int_reduce_kernel<<<GRID_CELLS / 256, 256, 0, stream>>>(partial, out);
    } else {
        float* partial = (float*)ws;
        int C = (int)(ws_size / gridBytes);
        if (C > MAXC) C = MAXC;
        if (C < 1) C = 1;
        slab_scatter_kernel<<<16 * C, TPB, 0, stream>>>(x, xr, n, C, partial);
        reduce_kernel<<<GRID_CELLS / 256, 256, 0, stream>>>(partial, C, out);
    }
}